// Round 2
// baseline (636.056 us; speedup 1.0000x reference)
//
#include <hip/hip_runtime.h>

// DIAGNOSTIC ROUND — deliberately slower. The single-pass kernel never appears
// in rocprof's top-5 (it's faster than the harness's 1 GiB poison fills), so
// its achieved store BW has never been measured. This build runs the identical
// body 5x per dispatch, twice (NT stores, then regular stores), so BOTH
// variants land in the top-5 with their own hbm_gbps / FETCH_SIZE / VALUBusy
// rows. Output correctness is unaffected: every pass writes identical correct
// values; the final writer is the regular-store kernel.
//
// out[l, i] = exp(l * A[i,i]) * B[i] * C[i] + D,  l in [0, L), i in [0, 256)

#define SSM_N 256
#define SSM_L 262144
#define SSM_GRID 2048
#define SSM_BLOCK 256
#define SSM_PASSES 5

typedef float f32x4 __attribute__((ext_vector_type(4)));

template <bool NT>
__global__ __launch_bounds__(SSM_BLOCK) void SSMKernel_56770877718744_kernel(
    const float* __restrict__ A,   // (256, 256), only diagonal used
    const float* __restrict__ B,   // (256, 1)
    const float* __restrict__ C,   // (1, 256)
    const float* __restrict__ D,   // (1,)
    float* __restrict__ out)       // (L, 256)
{
    const int t = threadIdx.x;
    const int q = t & 63;          // quad index within row: columns 4q..4q+3
    const int c = q << 2;          // column base
    const int r = t >> 6;          // sub-row 0..3 within a 4-row group

    const float LOG2E = 1.4426950408889634f;

    const float a0 = A[(size_t)(c + 0) * SSM_N + (c + 0)] * LOG2E;
    const float a1 = A[(size_t)(c + 1) * SSM_N + (c + 1)] * LOG2E;
    const float a2 = A[(size_t)(c + 2) * SSM_N + (c + 2)] * LOG2E;
    const float a3 = A[(size_t)(c + 3) * SSM_N + (c + 3)] * LOG2E;

    const float bc0 = B[c + 0] * C[c + 0];
    const float bc1 = B[c + 1] * C[c + 1];
    const float bc2 = B[c + 2] * C[c + 2];
    const float bc3 = B[c + 3] * C[c + 3];

    const float d = D[0];

    const int rows_per_block = SSM_L / SSM_GRID;   // 128
    const int row0 = blockIdx.x * rows_per_block + r;
    const int iters = rows_per_block / 4;          // 32

    for (int pass = 0; pass < SSM_PASSES; ++pass) {
        f32x4* __restrict__ p = (f32x4*)out + (size_t)row0 * 64 + q;
        float lf = (float)row0;                    // exact: row0 < 2^24

#pragma unroll 8
        for (int it = 0; it < iters; ++it) {
            f32x4 v;
            v.x = __builtin_amdgcn_exp2f(lf * a0) * bc0 + d;
            v.y = __builtin_amdgcn_exp2f(lf * a1) * bc1 + d;
            v.z = __builtin_amdgcn_exp2f(lf * a2) * bc2 + d;
            v.w = __builtin_amdgcn_exp2f(lf * a3) * bc3 + d;
            if (NT) {
                __builtin_nontemporal_store(v, p);
            } else {
                *p = v;
            }
            lf += 4.0f;
            p += 256;
        }
        // Keep every pass's stores live — without this, identical stores to
        // identical addresses in earlier passes are legal dead-store-elim
        // targets and the diagnostic would silently measure one pass.
        asm volatile("" ::: "memory");
    }
}

extern "C" void kernel_launch(void* const* d_in, const int* in_sizes, int n_in,
                              void* d_out, int out_size, void* d_ws, size_t ws_size,
                              hipStream_t stream) {
    // Inputs (setup_inputs order): L (int scalar), A (256x256 f32),
    // B (256x1 f32), C (1x256 f32), D (1 f32).
    const float* A = (const float*)d_in[1];
    const float* B = (const float*)d_in[2];
    const float* C = (const float*)d_in[3];
    const float* D = (const float*)d_in[4];
    float* out = (float*)d_out;

    // NT variant first, regular second (final output written by regular
    // stores; both write identical values). Two distinct mangled names ->
    // two distinct rows in the rocprof table.
    SSMKernel_56770877718744_kernel<true><<<SSM_GRID, SSM_BLOCK, 0, stream>>>(A, B, C, D, out);
    SSMKernel_56770877718744_kernel<false><<<SSM_GRID, SSM_BLOCK, 0, stream>>>(A, B, C, D, out);
}

// Round 3
// 616.998 us; speedup vs baseline: 1.0309x; 1.0309x over previous
//
#include <hip/hip_runtime.h>

// DIAGNOSTIC ROUND 2 (deliberately slower): A/B of write-stream topology.
//
// Round-2 finding: the compute kernel stores at 5.1 TB/s while the harness's
// memset fill hits 6.4-6.6 TB/s on the same chip. Occupancy/VALU/FETCH all
// exonerated by counters. Hypothesis: 2048 independent per-block write
// streams thrash DRAM row buffers; a memset-like globally-monotonic write
// front (whole grid covers one contiguous slab per grid-stride step) gets
// row-buffer locality.
//
// Two distinctly NAMED kernels (round 2's template variants shared a
// Kernel_Name and were indistinguishable in rocprof):
//   *_chunk: block owns 128 contiguous rows (current layout), 256 thr/blk
//   *_slab:  memset-like global-stride, 512 thr/blk (Workgroup_Size column
//            disambiguates too)
// Both run 5 passes to exceed the ~166 us fills and land in top-5 with their
// own counter rows. All passes write identical correct values.
//
// out[l, i] = exp(l * A[i,i]) * B[i] * C[i] + D,  l in [0, L), i in [0, 256)

#define SSM_N 256
#define SSM_L 262144
#define SSM_PASSES 5

typedef float f32x4 __attribute__((ext_vector_type(4)));

// ---------------------------------------------------------------- chunk ----
// Block b owns rows [b*128, b*128+128). Wave r writes rows r, r+4, ...
__global__ __launch_bounds__(256) void SSMKernel_56770877718744_chunk(
    const float* __restrict__ A, const float* __restrict__ B,
    const float* __restrict__ C, const float* __restrict__ D,
    float* __restrict__ out)
{
    const int t = threadIdx.x;
    const int q = t & 63;
    const int c = q << 2;
    const int r = t >> 6;

    const float LOG2E = 1.4426950408889634f;
    const float a0 = A[(size_t)(c + 0) * SSM_N + (c + 0)] * LOG2E;
    const float a1 = A[(size_t)(c + 1) * SSM_N + (c + 1)] * LOG2E;
    const float a2 = A[(size_t)(c + 2) * SSM_N + (c + 2)] * LOG2E;
    const float a3 = A[(size_t)(c + 3) * SSM_N + (c + 3)] * LOG2E;
    const float bc0 = B[c + 0] * C[c + 0];
    const float bc1 = B[c + 1] * C[c + 1];
    const float bc2 = B[c + 2] * C[c + 2];
    const float bc3 = B[c + 3] * C[c + 3];
    const float d = D[0];

    const int row0 = blockIdx.x * 128 + r;

    for (int pass = 0; pass < SSM_PASSES; ++pass) {
        f32x4* __restrict__ p = (f32x4*)out + (size_t)row0 * 64 + q;
        float lf = (float)row0;
#pragma unroll 8
        for (int it = 0; it < 32; ++it) {
            f32x4 v;
            v.x = __builtin_amdgcn_exp2f(lf * a0) * bc0 + d;
            v.y = __builtin_amdgcn_exp2f(lf * a1) * bc1 + d;
            v.z = __builtin_amdgcn_exp2f(lf * a2) * bc2 + d;
            v.w = __builtin_amdgcn_exp2f(lf * a3) * bc3 + d;
            *p = v;
            lf += 4.0f;
            p += 256;          // 4 rows
        }
        asm volatile("" ::: "memory");   // keep each pass's stores live
    }
}

// ----------------------------------------------------------------- slab ----
// Memset-like: global thread id g in [0, 524288); per grid-stride step the
// ENTIRE grid writes one contiguous 8 MiB slab, front advances monotonically.
// f32x4 index f = g + it*524288;  q = f & 63 = g & 63 (per-thread constant),
// l = (g >> 6) + it*8192  ->  lf += 8192.0f per step (exact, l < 2^24).
__global__ __launch_bounds__(512) void SSMKernel_56770877718744_slab(
    const float* __restrict__ A, const float* __restrict__ B,
    const float* __restrict__ C, const float* __restrict__ D,
    float* __restrict__ out)
{
    const int g = blockIdx.x * 512 + threadIdx.x;   // 1024 blocks * 512
    const int q = g & 63;
    const int c = q << 2;

    const float LOG2E = 1.4426950408889634f;
    const float a0 = A[(size_t)(c + 0) * SSM_N + (c + 0)] * LOG2E;
    const float a1 = A[(size_t)(c + 1) * SSM_N + (c + 1)] * LOG2E;
    const float a2 = A[(size_t)(c + 2) * SSM_N + (c + 2)] * LOG2E;
    const float a3 = A[(size_t)(c + 3) * SSM_N + (c + 3)] * LOG2E;
    const float bc0 = B[c + 0] * C[c + 0];
    const float bc1 = B[c + 1] * C[c + 1];
    const float bc2 = B[c + 2] * C[c + 2];
    const float bc3 = B[c + 3] * C[c + 3];
    const float d = D[0];

    const float lf0 = (float)(g >> 6);

    for (int pass = 0; pass < SSM_PASSES; ++pass) {
        f32x4* __restrict__ p = (f32x4*)out + g;
        float lf = lf0;
#pragma unroll 8
        for (int it = 0; it < 32; ++it) {
            f32x4 v;
            v.x = __builtin_amdgcn_exp2f(lf * a0) * bc0 + d;
            v.y = __builtin_amdgcn_exp2f(lf * a1) * bc1 + d;
            v.z = __builtin_amdgcn_exp2f(lf * a2) * bc2 + d;
            v.w = __builtin_amdgcn_exp2f(lf * a3) * bc3 + d;
            *p = v;
            lf += 8192.0f;     // exact integer increment
            p += 524288;       // whole-grid stride (8 MiB of f32x4)
        }
        asm volatile("" ::: "memory");
    }
}

extern "C" void kernel_launch(void* const* d_in, const int* in_sizes, int n_in,
                              void* d_out, int out_size, void* d_ws, size_t ws_size,
                              hipStream_t stream) {
    const float* A = (const float*)d_in[1];
    const float* B = (const float*)d_in[2];
    const float* C = (const float*)d_in[3];
    const float* D = (const float*)d_in[4];
    float* out = (float*)d_out;

    SSMKernel_56770877718744_chunk<<<2048, 256, 0, stream>>>(A, B, C, D, out);
    SSMKernel_56770877718744_slab <<<1024, 512, 0, stream>>>(A, B, C, D, out);
}

// Round 4
// 262.208 us; speedup vs baseline: 2.4258x; 2.3531x over previous
//
#include <hip/hip_runtime.h>

// out[l, i] = exp(l * A[i,i]) * B[i] * C[i] + D,  l in [0, L), i in [0, 256)
// L = 262144, n = 256. Output: 67.1M fp32 = 256 MiB -> HBM-write-bound.
//
// FINAL (post-diagnostic) layout — "slab" write topology, measured 6.15 TB/s
// (77% of peak, within ~4% of the memset fill's 6.4-6.6 TB/s on this chip)
// vs 5.1 TB/s for the per-block-chunk layout (round-3 A/B, 5-pass rocprof
// rows with per-kernel counters):
//
//   Global thread id g in [0, 524288); per grid-stride step the ENTIRE grid
//   writes one contiguous 8 MiB slab and the write front advances
//   monotonically through the 256 MiB output — memset-like DRAM row-buffer
//   locality. Per-block private chunk streams (old layout) interleave 2048
//   scattered streams per channel and lose ~16% BW.
//
//   f32x4 index f = g + it*524288; column quad q = f & 63 = g & 63 is a
//   per-thread constant, row l = (g >> 6) + it*8192 -> lf += 8192.0f per
//   step (exact: all l < 2^24).
//
// Compute is far off the critical path (VALUBusy 16% at 5-pass saturation):
// 4x v_exp_f32 per 16 B stored. NT stores measured neutral (round-2 A/B).

#define SSM_N 256
#define SSM_L 262144
#define SSM_BLOCK 512
#define SSM_GRID 1024          // 1024 * 512 threads = 524288 = L*256/4 per step

typedef float f32x4 __attribute__((ext_vector_type(4)));

__global__ __launch_bounds__(SSM_BLOCK) void SSMKernel_56770877718744_kernel(
    const float* __restrict__ A,   // (256, 256), only diagonal used
    const float* __restrict__ B,   // (256, 1)
    const float* __restrict__ C,   // (1, 256)
    const float* __restrict__ D,   // (1,)
    float* __restrict__ out)       // (L, 256)
{
    const int g = blockIdx.x * SSM_BLOCK + threadIdx.x;
    const int q = g & 63;          // column quad: columns 4q..4q+3
    const int c = q << 2;

    const float LOG2E = 1.4426950408889634f;

    // Per-column constants (loop-invariant; 256 distinct values, L1/L2-hit).
    const float a0 = A[(size_t)(c + 0) * SSM_N + (c + 0)] * LOG2E;
    const float a1 = A[(size_t)(c + 1) * SSM_N + (c + 1)] * LOG2E;
    const float a2 = A[(size_t)(c + 2) * SSM_N + (c + 2)] * LOG2E;
    const float a3 = A[(size_t)(c + 3) * SSM_N + (c + 3)] * LOG2E;

    const float bc0 = B[c + 0] * C[c + 0];
    const float bc1 = B[c + 1] * C[c + 1];
    const float bc2 = B[c + 2] * C[c + 2];
    const float bc3 = B[c + 3] * C[c + 3];

    const float d = D[0];

    f32x4* __restrict__ p = (f32x4*)out + g;
    float lf = (float)(g >> 6);    // starting row for this thread (exact)

#pragma unroll 8
    for (int it = 0; it < 32; ++it) {
        f32x4 v;
        v.x = __builtin_amdgcn_exp2f(lf * a0) * bc0 + d;
        v.y = __builtin_amdgcn_exp2f(lf * a1) * bc1 + d;
        v.z = __builtin_amdgcn_exp2f(lf * a2) * bc2 + d;
        v.w = __builtin_amdgcn_exp2f(lf * a3) * bc3 + d;
        *p = v;
        lf += 8192.0f;             // exact integer increment (l < 2^24)
        p += 524288;               // whole-grid stride: next 8 MiB slab
    }
}

extern "C" void kernel_launch(void* const* d_in, const int* in_sizes, int n_in,
                              void* d_out, int out_size, void* d_ws, size_t ws_size,
                              hipStream_t stream) {
    // Inputs (setup_inputs order): L (int scalar), A (256x256 f32),
    // B (256x1 f32), C (1x256 f32), D (1 f32).
    const float* A = (const float*)d_in[1];
    const float* B = (const float*)d_in[2];
    const float* C = (const float*)d_in[3];
    const float* D = (const float*)d_in[4];
    float* out = (float*)d_out;

    SSMKernel_56770877718744_kernel<<<SSM_GRID, SSM_BLOCK, 0, stream>>>(A, B, C, D, out);
}